// Round 3
// baseline (49772.934 us; speedup 1.0000x reference)
//
#include <hip/hip_runtime.h>
#include <cmath>
#include <cstdint>

typedef unsigned long long u64;
typedef uint32_t u32;
typedef uint16_t u16;

#define NB 16
#define NT 500
#define NIN 1024
#define NN 4096
#define NWORDS 64   // NN/64
#define FWORDS 16   // NIN/64
#define NBLK 256

// Per-wave u16 index-list regions in LDS (16B-aligned, +32 zero-pad room each):
#define E_OFF 0
#define E_CAP 3328   // max exc = 3276 (+32 pad)
#define I_OFF 3328
#define I_CAP 896    // max inh = 820 (+32 pad)
#define F_OFF 4224
#define F_CAP 1056   // max ff = 1024 (+32 pad)
#define L_TOT 5280   // u16 elements per wave -> 10560 B; x4 waves = 42240 B LDS

__global__ __launch_bounds__(256) void k_inmask(const float* __restrict__ in, u64* __restrict__ inmask){
  int idx = blockIdx.x * 256 + threadIdx.x;
  u64 bal = __ballot(in[idx] > 0.0f);
  if ((threadIdx.x & 63) == 0) inmask[idx >> 6] = bal;
}

// Zero mask triple-buffer + barrier counter; build excitatory word-mask. Grid: 16x256.
__global__ __launch_bounds__(256) void k_init(u64* __restrict__ rm, u32* __restrict__ barcnt,
                                              u64* __restrict__ excw, const int* __restrict__ ctype){
  int idx = blockIdx.x * 256 + threadIdx.x;   // 0..4095
  if (idx < 3 * NB * NWORDS) rm[idx] = 0ull;
  if (idx == 0) *barcnt = 0u;
  u64 bal = __ballot(ctype[idx] == 0);
  if ((threadIdx.x & 63) == 0) excw[idx >> 6] = bal;
}

// Build ascending row-index list (u16) from a 64x64-bit mask; zero-pad 32 entries.
__device__ __forceinline__ int build16(u64 bits, u16* __restrict__ L, int lane){
  int c = __popcll(bits), p = c;
#pragma unroll
  for (int d = 1; d < 64; d <<= 1){ int o = __shfl_up(p, d, 64); if (lane >= d) p += o; }
  int k = p - c;
  int tot = __shfl(p, 63, 64);
  u64 x = bits;
  u32 base = ((u32)lane) << 6;
  while (x){ int j = __builtin_ctzll(x); x &= x - 1; L[k++] = (u16)(base | (u32)j); }
  if (lane < 32) L[tot + lane] = 0;   // pads -> row 0 (safe load; masked at ACC)
  return tot;
}

// Sequential ascending-n fp32 add chain, 32-row groups, 3 rotating buffers
// (96 nominal outstanding loads; HW caps at 63 = max per-wave MLP depth).
// Bitwise identical to a plain ascending loop: loads reordered, adds in order,
// pad adds are +0.0f (identity: all partials >= +0).
__device__ __forceinline__ float chain16(const char* __restrict__ Wc,
                                         const u16* __restrict__ L,
                                         int cnt, u32 m4)
{
  float acc = 0.0f;
  const int ngrp = (cnt + 31) >> 5;
  if (ngrp <= 0) return acc;
  const int rem = cnt & 31;
  float A[32], B[32], C[32];

#define CS_LOAD(buf, g) { \
    const uint4* q4_ = (const uint4*)(L + ((g) << 5)); \
    _Pragma("unroll") \
    for (int q = 0; q < 4; ++q){ \
      uint4 pk = q4_[q]; \
      u32 w0 = pk.x, w1 = pk.y, w2 = pk.z, w3 = pk.w; \
      buf[q*8+0] = *(const float*)(Wc + (((w0 & 0xFFFFu) << 14) + m4)); \
      buf[q*8+1] = *(const float*)(Wc + (((w0 >> 16)     << 14) + m4)); \
      buf[q*8+2] = *(const float*)(Wc + (((w1 & 0xFFFFu) << 14) + m4)); \
      buf[q*8+3] = *(const float*)(Wc + (((w1 >> 16)     << 14) + m4)); \
      buf[q*8+4] = *(const float*)(Wc + (((w2 & 0xFFFFu) << 14) + m4)); \
      buf[q*8+5] = *(const float*)(Wc + (((w2 >> 16)     << 14) + m4)); \
      buf[q*8+6] = *(const float*)(Wc + (((w3 & 0xFFFFu) << 14) + m4)); \
      buf[q*8+7] = *(const float*)(Wc + (((w3 >> 16)     << 14) + m4)); \
    } }

#define CS_ACC(buf, g) { \
    if ((g) == ngrp - 1 && rem){ \
      _Pragma("unroll") \
      for (int j = 0; j < 32; ++j){ float pv_ = (j < rem) ? buf[j] : 0.0f; acc = __fadd_rn(acc, pv_); } \
    } else { \
      _Pragma("unroll") \
      for (int j = 0; j < 32; ++j) acc = __fadd_rn(acc, buf[j]); \
    } }

  CS_LOAD(A, 0)
  if (1 < ngrp) CS_LOAD(B, 1)
  if (2 < ngrp) CS_LOAD(C, 2)
  int g = 0;
  for (;;){
    CS_ACC(A, g)
    if (g + 3 < ngrp) CS_LOAD(A, g + 3)
    if (++g == ngrp) break;
    CS_ACC(B, g)
    if (g + 3 < ngrp) CS_LOAD(B, g + 3)
    if (++g == ngrp) break;
    CS_ACC(C, g)
    if (g + 3 < ngrp) CS_LOAD(C, g + 3)
    if (++g == ngrp) break;
  }
#undef CS_LOAD
#undef CS_ACC
  return acc;
}

// All 500 steps in one kernel. 256 blocks x 256 threads, all co-resident
// (256 CUs); grid sync via monotonic agent-scope counter. Only the spike
// bitmasks cross blocks -> triple-buffered, agent-scope atomics. Neuron
// state lives in registers for the whole simulation.
__global__ __launch_bounds__(256) void k_fused(
    const float* __restrict__ W, const float* __restrict__ Wff,
    const u64* __restrict__ excw, const u64* __restrict__ inmask,
    u64* __restrict__ rm, u32* __restrict__ barcnt,
    float* __restrict__ out,
    float a0, float a1, float aff, float beta, float omb)
{
  const int lane = threadIdx.x & 63;
  const int wv   = threadIdx.x >> 6;                 // local batch 0..3
  const int bk   = blockIdx.x;
  // XCD-aware: xcd = bk&7 -> XCD x owns columns [x*512, x*512+512) for all batches
  const int chunk = (bk & 7) * 8 + ((bk >> 3) & 7);  // 0..63
  const int b     = (bk >> 6) * 4 + wv;              // 0..15
  const int m     = chunk * 64 + lane;               // 0..4095
  const u32 m4    = (u32)(m << 2);

  __shared__ __align__(16) u16 lst[4][L_TOT];
  u16* Lb = lst[wv];

  const char* Wc  = (const char*)W;
  const char* Wfc = (const char*)Wff;
  const u64 ew = excw[lane];

  float vv = 0.0f, xi0 = 0.0f, xi1 = 0.0f, xff = 0.0f, rv = 0.0f;

  for (int t = 0; t < NT; ++t){
    u64* rcur = rm + (size_t)(t % 3)       * (NB * NWORDS);
    u64* rnxt = rm + (size_t)((t + 1) % 3) * (NB * NWORDS);

    u64 bits = __hip_atomic_load(&rcur[b * NWORDS + lane],
                                 __ATOMIC_RELAXED, __HIP_MEMORY_SCOPE_AGENT);
    u64 be = bits & ew;
    u64 bi = bits & ~ew;
    u64 bf = (lane < FWORDS) ? inmask[((size_t)b * NT + t) * FWORDS + lane] : 0ull;

    int tot_e = build16(be, Lb + E_OFF, lane);
    int tot_i = build16(bi, Lb + I_OFF, lane);
    int tot_f = build16(bf, Lb + F_OFF, lane);

    float de = chain16(Wc,  Lb + E_OFF, tot_e, m4);
    float di = chain16(Wc,  Lb + I_OFF, tot_i, m4);
    float df = chain16(Wfc, Lb + F_OFF, tot_f, m4);

    // I = alpha*I + drive  (separate mul/add roundings; -(sum of +W) == sum of -W bitwise)
    xi0 = __fadd_rn(__fmul_rn(a0,  xi0), de);
    xi1 = __fadd_rn(__fmul_rn(a1,  xi1), -di);
    xff = __fadd_rn(__fmul_rn(aff, xff), df);
    float itot = __fadd_rn(__fadd_rn(xi0, xi1), xff);
    float vn = (rv <= 0.0f) ? __fadd_rn(__fmul_rn(beta, vv), __fmul_rn(omb, itot)) : 0.0f;
    bool s = vn > 1.0f;                 // == (v_new - 1 > 0) exactly
    rv = s ? 2.0f : fmaxf(rv - 1.0f, 0.0f);
    vv = s ? 0.0f : vn;
    out[(size_t)b * NT * NN + (size_t)t * NN + m] = s ? 1.0f : 0.0f;

    u64 bal = __ballot(s);              // wave covers word 'chunk' of batch b
    if (lane == 0)
      __hip_atomic_store(&rnxt[b * NWORDS + chunk], bal,
                         __ATOMIC_RELAXED, __HIP_MEMORY_SCOPE_AGENT);

    // ---- grid barrier (monotonic counter; all 256 blocks resident) ----
    __syncthreads();                    // drains this block's stores (vmcnt 0)
    if (threadIdx.x == 0){
      __hip_atomic_fetch_add(barcnt, 1u, __ATOMIC_ACQ_REL, __HIP_MEMORY_SCOPE_AGENT);
      const u32 target = (u32)(t + 1) * NBLK;
      while (__hip_atomic_load(barcnt, __ATOMIC_ACQUIRE, __HIP_MEMORY_SCOPE_AGENT) < target)
        __builtin_amdgcn_s_sleep(1);
    }
    __syncthreads();
  }
}

extern "C" void kernel_launch(void* const* d_in, const int* in_sizes, int n_in,
                              void* d_out, int out_size, void* d_ws, size_t ws_size,
                              hipStream_t stream)
{
  const float* in_sp = (const float*)d_in[0];   // [16,500,1024]
  const float* W     = (const float*)d_in[1];   // [4096,4096]
  const float* Wff   = (const float*)d_in[2];   // [1024,4096]
  const int*   ctype = (const int*)d_in[3];     // [4096]
  float* out = (float*)d_out;

  char* ws = (char*)d_ws;
  u64* rm     = (u64*)ws;                                   // [3][NB][NWORDS]
  size_t off  = (size_t)3 * NB * NWORDS * 8;
  u64* excw   = (u64*)(ws + off); off += (size_t)NWORDS * 8;
  u64* inmask = (u64*)(ws + off); off += (size_t)NB * NT * FWORDS * 8;
  u32* barcnt = (u32*)(ws + off); off += 64;

  // Constants matching numpy semantics (validated bit-exact rounds 1-2):
  float af  = -1.0f / 5.0f;
  float bf  = -1.0f / 10.0f;
  float a0  = (float)std::exp((double)af);
  float a1  = (float)std::exp((double)bf);
  float aff = (float)std::exp(-1.0 / 5.0);
  float beta = (float)std::exp(-1.0 / 20.0);
  float omb  = 1.0f - beta;   // exact (Sterbenz)

  k_inmask<<<(NB * NT * NIN) / 256, 256, 0, stream>>>(in_sp, inmask);
  k_init<<<16, 256, 0, stream>>>(rm, barcnt, excw, ctype);
  k_fused<<<NBLK, 256, 0, stream>>>(W, Wff, excw, inmask, rm, barcnt, out,
                                    a0, a1, aff, beta, omb);
}

// Round 4
// 25119.072 us; speedup vs baseline: 1.9815x; 1.9815x over previous
//
#include <hip/hip_runtime.h>
#include <cmath>
#include <cstdint>

typedef unsigned long long u64;
typedef uint32_t u32;
typedef uint16_t u16;

#define NB 16
#define NT 500
#define NIN 1024
#define NN 4096
#define NWORDS 64   // NN/64
#define FWORDS 16   // NIN/64
#define NBLK 256
#define GBLK 64     // blocks per independent batch-group barrier

// Per-wave u16 index-list regions in LDS (16B-aligned, +32 zero-pad room each):
#define E_OFF 0
#define I_OFF 3328
#define F_OFF 4224
#define L_TOT 5280   // u16 per wave -> 10560 B; x4 waves = 42240 B LDS

__global__ __launch_bounds__(256) void k_inmask(const float* __restrict__ in, u64* __restrict__ inmask){
  int idx = blockIdx.x * 256 + threadIdx.x;
  u64 bal = __ballot(in[idx] > 0.0f);
  if ((threadIdx.x & 63) == 0) inmask[idx >> 6] = bal;
}

// Zero mask triple-buffer + barrier counters; build excitatory word-mask. Grid: 16x256.
__global__ __launch_bounds__(256) void k_init(u64* __restrict__ rm, u32* __restrict__ barcnt,
                                              u64* __restrict__ excw, const int* __restrict__ ctype){
  int idx = blockIdx.x * 256 + threadIdx.x;   // 0..4095
  if (idx < 3 * NB * NWORDS) rm[idx] = 0ull;
  if (idx < 128) barcnt[idx] = 0u;            // 4 counters, 32 u32 (128B) apart
  u64 bal = __ballot(ctype[idx] == 0);
  if ((threadIdx.x & 63) == 0) excw[idx >> 6] = bal;
}

// Build ascending row-index list (u16) from a 64x64-bit mask; zero-pad 32 entries.
__device__ __forceinline__ int build16(u64 bits, u16* __restrict__ L, int lane){
  int c = __popcll(bits), p = c;
#pragma unroll
  for (int d = 1; d < 64; d <<= 1){ int o = __shfl_up(p, d, 64); if (lane >= d) p += o; }
  int k = p - c;
  int tot = __shfl(p, 63, 64);
  u64 x = bits;
  u32 base = ((u32)lane) << 6;
  while (x){ int j = __builtin_ctzll(x); x &= x - 1; L[k++] = (u16)(base | (u32)j); }
  if (lane < 32) L[tot + lane] = 0;   // pads -> row 0 (safe load; masked at ACC)
  return tot;
}

// Sequential ascending-n fp32 add chain, 32-row groups, 3 rotating register
// buffers (deep MLP). Bitwise identical to a plain ascending loop: only load
// issue is reordered; adds stay in order; pad adds are +0.0f (identity: all
// partials >= +0).
__device__ __forceinline__ float chain16(const char* __restrict__ Wc,
                                         const u16* __restrict__ L,
                                         int cnt, u32 m4)
{
  float acc = 0.0f;
  const int ngrp = (cnt + 31) >> 5;
  if (ngrp <= 0) return acc;
  const int rem = cnt & 31;
  float A[32], B[32], C[32];

#define CS_LOAD(buf, g) { \
    const uint4* q4_ = (const uint4*)(L + ((g) << 5)); \
    _Pragma("unroll") \
    for (int q = 0; q < 4; ++q){ \
      uint4 pk = q4_[q]; \
      u32 w0 = pk.x, w1 = pk.y, w2 = pk.z, w3 = pk.w; \
      buf[q*8+0] = *(const float*)(Wc + (((w0 & 0xFFFFu) << 14) + m4)); \
      buf[q*8+1] = *(const float*)(Wc + (((w0 >> 16)     << 14) + m4)); \
      buf[q*8+2] = *(const float*)(Wc + (((w1 & 0xFFFFu) << 14) + m4)); \
      buf[q*8+3] = *(const float*)(Wc + (((w1 >> 16)     << 14) + m4)); \
      buf[q*8+4] = *(const float*)(Wc + (((w2 & 0xFFFFu) << 14) + m4)); \
      buf[q*8+5] = *(const float*)(Wc + (((w2 >> 16)     << 14) + m4)); \
      buf[q*8+6] = *(const float*)(Wc + (((w3 & 0xFFFFu) << 14) + m4)); \
      buf[q*8+7] = *(const float*)(Wc + (((w3 >> 16)     << 14) + m4)); \
    } }

#define CS_ACC(buf, g) { \
    if ((g) == ngrp - 1 && rem){ \
      _Pragma("unroll") \
      for (int j = 0; j < 32; ++j){ float pv_ = (j < rem) ? buf[j] : 0.0f; acc = __fadd_rn(acc, pv_); } \
    } else { \
      _Pragma("unroll") \
      for (int j = 0; j < 32; ++j) acc = __fadd_rn(acc, buf[j]); \
    } }

  CS_LOAD(A, 0)
  if (1 < ngrp) CS_LOAD(B, 1)
  if (2 < ngrp) CS_LOAD(C, 2)
  int g = 0;
  for (;;){
    CS_ACC(A, g)
    if (g + 3 < ngrp) CS_LOAD(A, g + 3)
    if (++g == ngrp) break;
    CS_ACC(B, g)
    if (g + 3 < ngrp) CS_LOAD(B, g + 3)
    if (++g == ngrp) break;
    CS_ACC(C, g)
    if (g + 3 < ngrp) CS_LOAD(C, g + 3)
    if (++g == ngrp) break;
  }
#undef CS_LOAD
#undef CS_ACC
  return acc;
}

// All 500 steps in one kernel. 256 blocks x 256 threads, all co-resident.
// __launch_bounds__(256, 1): 1 block/CU anyway -> full 512-VGPR budget so the
// 96-float pipeline buffers stay in registers (round 3 spilled at VGPR=80).
// Blocks bk>>6 form 4 independent batch-groups; each syncs on its own counter.
__global__ __launch_bounds__(256, 1) void k_fused(
    const float* __restrict__ W, const float* __restrict__ Wff,
    const u64* __restrict__ excw, const u64* __restrict__ inmask,
    u64* __restrict__ rm, u32* __restrict__ barcnt,
    float* __restrict__ out,
    float a0, float a1, float aff, float beta, float omb)
{
  const int lane = threadIdx.x & 63;
  const int wv   = threadIdx.x >> 6;                 // local batch 0..3
  const int bk   = blockIdx.x;
  // XCD-aware: xcd = bk&7 -> XCD x owns columns [x*512, x*512+512) for all batches
  const int chunk = (bk & 7) * 8 + ((bk >> 3) & 7);  // 0..63
  const int grp   = bk >> 6;                         // batch-group 0..3
  const int b     = grp * 4 + wv;                    // 0..15
  const int m     = chunk * 64 + lane;               // 0..4095
  const u32 m4    = (u32)(m << 2);

  __shared__ __align__(16) u16 lst[4][L_TOT];
  u16* Lb = lst[wv];

  const char* Wc  = (const char*)W;
  const char* Wfc = (const char*)Wff;
  const u64 ew = excw[lane];
  u32* mybar = barcnt + grp * 32;                    // 128B apart

  float vv = 0.0f, xi0 = 0.0f, xi1 = 0.0f, xff = 0.0f, rv = 0.0f;

  for (int t = 0; t < NT; ++t){
    u64* rcur = rm + (size_t)(t % 3)       * (NB * NWORDS);
    u64* rnxt = rm + (size_t)((t + 1) % 3) * (NB * NWORDS);

    u64 bits = __hip_atomic_load(&rcur[b * NWORDS + lane],
                                 __ATOMIC_RELAXED, __HIP_MEMORY_SCOPE_AGENT);
    u64 be = bits & ew;
    u64 bi = bits & ~ew;
    u64 bf = (lane < FWORDS) ? inmask[((size_t)b * NT + t) * FWORDS + lane] : 0ull;

    int tot_e = build16(be, Lb + E_OFF, lane);
    int tot_i = build16(bi, Lb + I_OFF, lane);
    int tot_f = build16(bf, Lb + F_OFF, lane);

    float de = chain16(Wc,  Lb + E_OFF, tot_e, m4);
    float di = chain16(Wc,  Lb + I_OFF, tot_i, m4);
    float df = chain16(Wfc, Lb + F_OFF, tot_f, m4);

    // I = alpha*I + drive  (separate mul/add roundings; -(sum of +W) == sum of -W bitwise)
    xi0 = __fadd_rn(__fmul_rn(a0,  xi0), de);
    xi1 = __fadd_rn(__fmul_rn(a1,  xi1), -di);
    xff = __fadd_rn(__fmul_rn(aff, xff), df);
    float itot = __fadd_rn(__fadd_rn(xi0, xi1), xff);
    float vn = (rv <= 0.0f) ? __fadd_rn(__fmul_rn(beta, vv), __fmul_rn(omb, itot)) : 0.0f;
    bool s = vn > 1.0f;                 // == (v_new - 1 > 0) exactly
    rv = s ? 2.0f : fmaxf(rv - 1.0f, 0.0f);
    vv = s ? 0.0f : vn;
    out[(size_t)b * NT * NN + (size_t)t * NN + m] = s ? 1.0f : 0.0f;

    u64 bal = __ballot(s);              // wave covers word 'chunk' of batch b
    if (lane == 0)
      __hip_atomic_store(&rnxt[b * NWORDS + chunk], bal,
                         __ATOMIC_RELAXED, __HIP_MEMORY_SCOPE_AGENT);

    // ---- per-group barrier (64 blocks; monotonic counter) ----
    __syncthreads();
    if (threadIdx.x == 0){
      __hip_atomic_fetch_add(mybar, 1u, __ATOMIC_ACQ_REL, __HIP_MEMORY_SCOPE_AGENT);
      const u32 target = (u32)(t + 1) * GBLK;
      while (__hip_atomic_load(mybar, __ATOMIC_ACQUIRE, __HIP_MEMORY_SCOPE_AGENT) < target)
        __builtin_amdgcn_s_sleep(1);
    }
    __syncthreads();
  }
}

extern "C" void kernel_launch(void* const* d_in, const int* in_sizes, int n_in,
                              void* d_out, int out_size, void* d_ws, size_t ws_size,
                              hipStream_t stream)
{
  const float* in_sp = (const float*)d_in[0];   // [16,500,1024]
  const float* W     = (const float*)d_in[1];   // [4096,4096]
  const float* Wff   = (const float*)d_in[2];   // [1024,4096]
  const int*   ctype = (const int*)d_in[3];     // [4096]
  float* out = (float*)d_out;

  char* ws = (char*)d_ws;
  u64* rm     = (u64*)ws;                                   // [3][NB][NWORDS]
  size_t off  = (size_t)3 * NB * NWORDS * 8;
  u64* excw   = (u64*)(ws + off); off += (size_t)NWORDS * 8;
  u64* inmask = (u64*)(ws + off); off += (size_t)NB * NT * FWORDS * 8;
  u32* barcnt = (u32*)(ws + off); off += 512;               // 4 counters, 128B apart

  // Constants matching numpy semantics (validated bit-exact rounds 1-3):
  float af  = -1.0f / 5.0f;
  float bf  = -1.0f / 10.0f;
  float a0  = (float)std::exp((double)af);
  float a1  = (float)std::exp((double)bf);
  float aff = (float)std::exp(-1.0 / 5.0);
  float beta = (float)std::exp(-1.0 / 20.0);
  float omb  = 1.0f - beta;   // exact (Sterbenz)

  k_inmask<<<(NB * NT * NIN) / 256, 256, 0, stream>>>(in_sp, inmask);
  k_init<<<16, 256, 0, stream>>>(rm, barcnt, excw, ctype);
  k_fused<<<NBLK, 256, 0, stream>>>(W, Wff, excw, inmask, rm, barcnt, out,
                                    a0, a1, aff, beta, omb);
}